// Round 1
// baseline (267.341 us; speedup 1.0000x reference)
//
#include <hip/hip_runtime.h>
#include <hip/hip_bf16.h>

// Shapes: B=512, BAG=32, H=1024, C=53.  EPS=1e-8, scale=sqrt(1024)=32.
// Inputs: 0 sent(B,BAG,H) f32, 1 aug f32, 2 rel_table(C,H) f32, 3 cls_w(C,H) f32,
//         4 cls_b(C) f32, 5 labels(B) i32, 6 temperature f32[1]
// Out: bag_out (512*53=27136) f32, then cl_loss scalar -> 27137 floats.

typedef __bf16 bf16x8 __attribute__((ext_vector_type(8)));
typedef float  f32x4  __attribute__((ext_vector_type(4)));

__device__ inline float wsum(float v) {
    #pragma unroll
    for (int off = 32; off > 0; off >>= 1) v += __shfl_xor(v, off, 64);
    return v;
}

// ---- k1: per-b attention softmax -> bag_reps (f32 + bf16) + nb ----
__global__ __launch_bounds__(1024) void k1_bag(
    const float* __restrict__ sent, const float* __restrict__ rel_table,
    const int* __restrict__ labels, float* __restrict__ bag,
    __bf16* __restrict__ bagb, float* __restrict__ nb)
{
    const int b = blockIdx.x, t = threadIdx.x;       // t = h in [0,1024)
    const int lane = t & 63, wave = t >> 6;          // 16 waves
    __shared__ float red[32 * 16];
    __shared__ float alphas[32];
    __shared__ float r2[16];

    const float relh = rel_table[(size_t)labels[b] * 1024 + t];
    const float* s = sent + (size_t)b * 32 * 1024;
    float v[32];
    #pragma unroll
    for (int j = 0; j < 32; j++) v[j] = s[j * 1024 + t];

    #pragma unroll
    for (int j = 0; j < 32; j++) {
        float p = wsum(relh * v[j]);
        if (lane == 0) red[j * 16 + wave] = p;
    }
    __syncthreads();

    if (wave == 0) {
        float sj = 0.0f;
        if (lane < 32) {
            #pragma unroll
            for (int w = 0; w < 16; w++) sj += red[lane * 16 + w];
            sj *= (1.0f / 32.0f);                    // /sqrt(H)
        }
        // softmax across lanes 0..31 (width-32 groups keep 32..63 separate)
        float m = sj;
        #pragma unroll
        for (int off = 16; off > 0; off >>= 1) m = fmaxf(m, __shfl_xor(m, off, 32));
        float e = __expf(sj - m);
        float sum = e;
        #pragma unroll
        for (int off = 16; off > 0; off >>= 1) sum += __shfl_xor(sum, off, 32);
        if (lane < 32) alphas[lane] = e / sum;
    }
    __syncthreads();

    float bg = 0.0f;
    #pragma unroll
    for (int j = 0; j < 32; j++) bg += alphas[j] * v[j];
    bag[(size_t)b * 1024 + t] = bg;
    bagb[(size_t)b * 1024 + t] = (__bf16)bg;

    float q = wsum(bg * bg);
    if (lane == 0) r2[wave] = q;
    __syncthreads();
    if (t == 0) {
        float s2 = 0.0f;
        #pragma unroll
        for (int w = 0; w < 16; w++) s2 += r2[w];
        nb[b] = sqrtf(s2);
    }
}

// ---- k2: per-(b,j) norms + pos_sim; repack rep to bf16 ----
__global__ __launch_bounds__(256) void k2_norms(
    const float* __restrict__ sent, const float* __restrict__ aug,
    __bf16* __restrict__ repb, float* __restrict__ nr, float* __restrict__ pos_sim)
{
    const int r = blockIdx.x;                        // 0..16383 = b*32+j
    const int t = threadIdx.x;
    const float* rp = sent + (size_t)r * 1024;
    const float* ap = aug + (size_t)r * 1024;
    float sr = 0.f, sa = 0.f, sd = 0.f;
    #pragma unroll
    for (int i = 0; i < 4; i++) {
        int h = t + i * 256;
        float x = rp[h], y = ap[h];
        sr += x * x; sa += y * y; sd += x * y;
        repb[(size_t)r * 1024 + h] = (__bf16)x;
    }
    sr = wsum(sr); sa = wsum(sa); sd = wsum(sd);
    __shared__ float red[4 * 3];
    const int lane = t & 63, wave = t >> 6;
    if (lane == 0) { red[wave * 3] = sr; red[wave * 3 + 1] = sa; red[wave * 3 + 2] = sd; }
    __syncthreads();
    if (t == 0) {
        float S = 0.f, A = 0.f, D = 0.f;
        #pragma unroll
        for (int w = 0; w < 4; w++) { S += red[w * 3]; A += red[w * 3 + 1]; D += red[w * 3 + 2]; }
        float nrv = sqrtf(S), nav = sqrtf(A);
        nr[r] = nrv;
        pos_sim[r] = D / fmaxf(nrv * nav, 1e-8f);
    }
}

// ---- k3: bag_out = bag @ cls_w^T + cls_b ----
__global__ __launch_bounds__(64) void k3_cls(
    const float* __restrict__ bag, const float* __restrict__ w,
    const float* __restrict__ bias, float* __restrict__ out)
{
    const int b = blockIdx.x, lane = threadIdx.x;
    float acc[53];
    #pragma unroll
    for (int c = 0; c < 53; c++) acc[c] = 0.f;
    for (int it = 0; it < 16; it++) {
        float bv = bag[(size_t)b * 1024 + it * 64 + lane];
        #pragma unroll
        for (int c = 0; c < 53; c++) acc[c] += bv * w[(size_t)c * 1024 + it * 64 + lane];
    }
    float mine = 0.f;
    #pragma unroll
    for (int c = 0; c < 53; c++) {
        float rsum = wsum(acc[c]);
        if (lane == c) mine = rsum;
    }
    if (lane < 53) out[(size_t)b * 53 + lane] = mine + bias[lane];
}

// ---- k4: E[r][c] = exp( (rep[r]·bag[c]) / max(nb[c]*nr[r],eps) / T ) via bf16 MFMA ----
__global__ __launch_bounds__(256) void k4_gemm(
    const __bf16* __restrict__ repb, const __bf16* __restrict__ bagb,
    const float* __restrict__ nr, const float* __restrict__ nb,
    const float* __restrict__ temp, float* __restrict__ E)
{
    __shared__ __align__(16) __bf16 Al[64 * 40];   // 64 rows, K-chunk 32, pad to 40
    __shared__ __align__(16) __bf16 Bl[64 * 40];
    const int cb = blockIdx.x;                      // 0..7   (cols of bag)
    const int rb = blockIdx.y;                      // 0..255 (rows of rep)
    const int r0 = rb * 64, c0 = cb * 64;
    const int t = threadIdx.x;
    const int lane = t & 63, w = t >> 6;            // 4 waves: rows w*16..+16
    const int m = lane & 15, quad = lane >> 4;

    f32x4 acc[4] = {};
    const int lrow = t >> 2;                        // 0..63
    const int lk = (t & 3) * 8;                     // 0,8,16,24

    for (int k0 = 0; k0 < 1024; k0 += 32) {
        __syncthreads();
        *(f32x4*)(&Al[lrow * 40 + lk]) = *(const f32x4*)(&repb[(size_t)(r0 + lrow) * 1024 + k0 + lk]);
        *(f32x4*)(&Bl[lrow * 40 + lk]) = *(const f32x4*)(&bagb[(size_t)(c0 + lrow) * 1024 + k0 + lk]);
        __syncthreads();
        bf16x8 a = *(const bf16x8*)(&Al[(w * 16 + m) * 40 + quad * 8]);
        #pragma unroll
        for (int n = 0; n < 4; n++) {
            bf16x8 bf = *(const bf16x8*)(&Bl[(n * 16 + m) * 40 + quad * 8]);
            acc[n] = __builtin_amdgcn_mfma_f32_16x16x32_bf16(a, bf, acc[n], 0, 0, 0);
        }
    }

    const float invT = 1.0f / *temp;
    float nrv[4];
    #pragma unroll
    for (int i = 0; i < 4; i++) nrv[i] = nr[r0 + w * 16 + quad * 4 + i];
    #pragma unroll
    for (int n = 0; n < 4; n++) {
        const int c = c0 + n * 16 + m;
        const float nbv = nb[c];
        #pragma unroll
        for (int i = 0; i < 4; i++) {
            const int r = r0 + w * 16 + quad * 4 + i;
            float pair = acc[n][i] / fmaxf(nbv * nrv[i], 1e-8f);
            E[(size_t)r * 512 + c] = __expf(pair * invT);
        }
    }
}

// ---- k5: neg[c][j] = sum_b E[b*32+j][c] - E[c*32+j][c]; per-element loss; block sums ----
__global__ __launch_bounds__(256) void k5_neg(
    const float* __restrict__ E, const float* __restrict__ pos_sim,
    const float* __restrict__ temp, float* __restrict__ bsums)
{
    const int tid = blockIdx.x * 256 + threadIdx.x;  // 0..16383
    const int c = tid & 511, j = tid >> 9;
    float s = 0.f;
    for (int b = 0; b < 512; b++) s += E[(size_t)((b << 5) + j) * 512 + c];
    s -= E[(size_t)((c << 5) + j) * 512 + c];        // exact diagonal cancellation
    const float T = *temp;
    const float lp = pos_sim[(c << 5) + j] / T;      // log(pos)
    const float pos = __expf(lp);
    float term = logf(pos + s) - lp;                 // -log(pos/(pos+neg))
    term = wsum(term);
    __shared__ float red[4];
    if ((threadIdx.x & 63) == 0) red[threadIdx.x >> 6] = term;
    __syncthreads();
    if (threadIdx.x == 0) bsums[blockIdx.x] = red[0] + red[1] + red[2] + red[3];
}

__global__ __launch_bounds__(64) void k6_final(const float* __restrict__ bsums, float* __restrict__ loss)
{
    float v = bsums[threadIdx.x];
    v = wsum(v);
    if (threadIdx.x == 0) *loss = v * (1.0f / 16384.0f);
}

extern "C" void kernel_launch(void* const* d_in, const int* in_sizes, int n_in,
                              void* d_out, int out_size, void* d_ws, size_t ws_size,
                              hipStream_t stream)
{
    const float* sent = (const float*)d_in[0];
    const float* aug  = (const float*)d_in[1];
    const float* rel  = (const float*)d_in[2];
    const float* clsw = (const float*)d_in[3];
    const float* clsb = (const float*)d_in[4];
    const int*   lab  = (const int*)d_in[5];
    const float* temp = (const float*)d_in[6];
    float* out = (float*)d_out;

    // workspace layout (bytes): ~70.4 MB total
    char* ws = (char*)d_ws;
    float*  bag   = (float*)(ws);                        // 512*1024*4   = 2 MB
    __bf16* bagb  = (__bf16*)(ws + (2u << 20));          // 512*1024*2   = 1 MB
    float*  nb    = (float*)(ws + (3u << 20));           // 2 KB
    float*  nr    = (float*)(ws + (3u << 20) + 65536);   // 64 KB
    float*  pos   = (float*)(ws + (3u << 20) + 2*65536); // 64 KB
    __bf16* repb  = (__bf16*)(ws + (4u << 20));          // 16384*1024*2 = 32 MB
    float*  E     = (float*)(ws + (36u << 20));          // 16384*512*4  = 32 MB
    float*  bsums = (float*)(ws + (68u << 20));          // 256 B

    k1_bag  <<<512, 1024, 0, stream>>>(sent, rel, lab, bag, bagb, nb);
    k2_norms<<<16384, 256, 0, stream>>>(sent, aug, repb, nr, pos);
    k3_cls  <<<512, 64, 0, stream>>>(bag, clsw, clsb, out);
    k4_gemm <<<dim3(8, 256), 256, 0, stream>>>(repb, bagb, nr, nb, temp, E);
    k5_neg  <<<64, 256, 0, stream>>>(E, pos, temp, bsums);
    k6_final<<<1, 64, 0, stream>>>(bsums, out + 27136);
}

// Round 2
// 229.601 us; speedup vs baseline: 1.1644x; 1.1644x over previous
//
#include <hip/hip_runtime.h>
#include <hip/hip_bf16.h>

// Shapes: B=512, BAG=32, H=1024, C=53.  EPS=1e-8, scale=sqrt(1024)=32.
// Out: bag_out (512*53=27136) f32, then cl_loss scalar -> 27137 floats.

typedef __bf16 bf16x8 __attribute__((ext_vector_type(8)));
typedef float  f32x4  __attribute__((ext_vector_type(4)));

__device__ inline float wsum(float v) {
    #pragma unroll
    for (int off = 32; off > 0; off >>= 1) v += __shfl_xor(v, off, 64);
    return v;
}

__device__ inline void gll16(const void* g, void* l) {
    __builtin_amdgcn_global_load_lds((const __attribute__((address_space(1))) void*)g,
                                     (__attribute__((address_space(3))) void*)l, 16, 0, 0);
}

// ---- k0: cls_w -> bf16, padded to 64 rows (rows 53..63 zero) ----
__global__ __launch_bounds__(256) void k0_cvt(const float* __restrict__ w, __bf16* __restrict__ wb)
{
    int i = blockIdx.x * 256 + threadIdx.x;            // 65536 total
    wb[i] = (i < 53 * 1024) ? (__bf16)w[i] : (__bf16)0.0f;
}

// ---- k1: per-b attention softmax -> bag_reps (f32 + bf16) + nb ----
__global__ __launch_bounds__(1024) void k1_bag(
    const float* __restrict__ sent, const float* __restrict__ rel_table,
    const int* __restrict__ labels, float* __restrict__ bag,
    __bf16* __restrict__ bagb, float* __restrict__ nb)
{
    const int b = blockIdx.x, t = threadIdx.x;         // t = h in [0,1024)
    const int lane = t & 63, wave = t >> 6;            // 16 waves
    __shared__ float red[32 * 16];
    __shared__ float alphas[32];
    __shared__ float r2[16];

    const float relh = rel_table[(size_t)labels[b] * 1024 + t];
    const float* s = sent + (size_t)b * 32 * 1024;
    float v[32];
    #pragma unroll
    for (int j = 0; j < 32; j++) v[j] = s[j * 1024 + t];

    #pragma unroll
    for (int j = 0; j < 32; j++) {
        float p = wsum(relh * v[j]);
        if (lane == 0) red[j * 16 + wave] = p;
    }
    __syncthreads();

    if (wave == 0) {
        float sj = 0.0f;
        if (lane < 32) {
            #pragma unroll
            for (int w = 0; w < 16; w++) sj += red[lane * 16 + w];
            sj *= (1.0f / 32.0f);                      // /sqrt(H)
        }
        float m = sj;
        #pragma unroll
        for (int off = 16; off > 0; off >>= 1) m = fmaxf(m, __shfl_xor(m, off, 32));
        float e = __expf(sj - m);
        float sum = e;
        #pragma unroll
        for (int off = 16; off > 0; off >>= 1) sum += __shfl_xor(sum, off, 32);
        if (lane < 32) alphas[lane] = e / sum;
    }
    __syncthreads();

    float bg = 0.0f;
    #pragma unroll
    for (int j = 0; j < 32; j++) bg += alphas[j] * v[j];
    bag[(size_t)b * 1024 + t] = bg;
    bagb[(size_t)b * 1024 + t] = (__bf16)bg;

    float q = wsum(bg * bg);
    if (lane == 0) r2[wave] = q;
    __syncthreads();
    if (t == 0) {
        float s2 = 0.0f;
        #pragma unroll
        for (int w = 0; w < 16; w++) s2 += r2[w];
        nb[b] = sqrtf(s2);
    }
}

// ---- k2: per-(b,j) norms + pos_sim; repack rep to bf16 ----
__global__ __launch_bounds__(256) void k2_norms(
    const float* __restrict__ sent, const float* __restrict__ aug,
    __bf16* __restrict__ repb, float* __restrict__ nr, float* __restrict__ pos_sim)
{
    const int r = blockIdx.x;                          // 0..16383
    const int t = threadIdx.x;
    const float* rp = sent + (size_t)r * 1024;
    const float* ap = aug + (size_t)r * 1024;
    float sr = 0.f, sa = 0.f, sd = 0.f;
    #pragma unroll
    for (int i = 0; i < 4; i++) {
        int h = t + i * 256;
        float x = rp[h], y = ap[h];
        sr += x * x; sa += y * y; sd += x * y;
        repb[(size_t)r * 1024 + h] = (__bf16)x;
    }
    sr = wsum(sr); sa = wsum(sa); sd = wsum(sd);
    __shared__ float red[4 * 3];
    const int lane = t & 63, wave = t >> 6;
    if (lane == 0) { red[wave * 3] = sr; red[wave * 3 + 1] = sa; red[wave * 3 + 2] = sd; }
    __syncthreads();
    if (t == 0) {
        float S = 0.f, A = 0.f, D = 0.f;
        #pragma unroll
        for (int w = 0; w < 4; w++) { S += red[w * 3]; A += red[w * 3 + 1]; D += red[w * 3 + 2]; }
        float nrv = sqrtf(S), nav = sqrtf(A);
        nr[r] = nrv;
        pos_sim[r] = D / fmaxf(nrv * nav, 1e-8f);
    }
}

// ---- k3m: bag_out = bagb @ cwb^T + cls_b via MFMA (64x64 tile per block) ----
__global__ __launch_bounds__(256) void k3m(
    const __bf16* __restrict__ bagb, const __bf16* __restrict__ cwb,
    const float* __restrict__ bias, float* __restrict__ out)
{
    __shared__ __align__(16) __bf16 Al[64 * 40];
    __shared__ __align__(16) __bf16 Bl[64 * 40];
    const int r0 = blockIdx.x * 64;                    // 8 blocks
    const int t = threadIdx.x, lane = t & 63, w = t >> 6;
    const int m = lane & 15, quad = lane >> 4;
    f32x4 acc[4] = {};
    const int lrow = t >> 2, lk = (t & 3) * 8;

    for (int k0 = 0; k0 < 1024; k0 += 32) {
        __syncthreads();
        *(f32x4*)(&Al[lrow * 40 + lk]) = *(const f32x4*)(&bagb[(size_t)(r0 + lrow) * 1024 + k0 + lk]);
        *(f32x4*)(&Bl[lrow * 40 + lk]) = *(const f32x4*)(&cwb[(size_t)lrow * 1024 + k0 + lk]);
        __syncthreads();
        bf16x8 a = *(const bf16x8*)(&Al[(w * 16 + m) * 40 + quad * 8]);
        #pragma unroll
        for (int n = 0; n < 4; n++) {
            bf16x8 bf = *(const bf16x8*)(&Bl[(n * 16 + m) * 40 + quad * 8]);
            acc[n] = __builtin_amdgcn_mfma_f32_16x16x32_bf16(a, bf, acc[n], 0, 0, 0);
        }
    }
    #pragma unroll
    for (int n = 0; n < 4; n++) {
        const int c = n * 16 + m;
        if (c < 53) {
            #pragma unroll
            for (int i = 0; i < 4; i++) {
                const int r = r0 + w * 16 + quad * 4 + i;
                out[(size_t)r * 53 + c] = acc[n][i] + bias[c];
            }
        }
    }
}

// ---- k4: E = exp(pair/T) via bf16 MFMA, 128x128 tile, global_load_lds staging ----
__global__ __launch_bounds__(256) void k4_gemm(
    const __bf16* __restrict__ repb, const __bf16* __restrict__ bagb,
    const float* __restrict__ nr, const float* __restrict__ nb,
    const float* __restrict__ temp, float* __restrict__ E)
{
    __shared__ __align__(16) __bf16 Al[128 * 32];      // [row][k], NO pad (global_load_lds)
    __shared__ __align__(16) __bf16 Bl[128 * 32];
    const int cb = blockIdx.x, rb = blockIdx.y;        // 4 x 128
    const int r0 = rb * 128, c0 = cb * 128;
    const int t = threadIdx.x, lane = t & 63, w = t >> 6;
    const int m = lane & 15, quad = lane >> 4;
    const int wr0 = (w & 1) * 64, wc0 = (w >> 1) * 64; // 2x2 wave grid

    f32x4 acc[4][4] = {};

    // staging: round r covers tile bf16 idx [r*2048 + t*8, +8)
    const int i0 = t * 8, i1 = 2048 + t * 8;
    const int row0 = i0 >> 5, kk0 = i0 & 31;
    const int row1 = i1 >> 5, kk1 = i1 & 31;
    const __bf16* gA0 = repb + (size_t)(r0 + row0) * 1024 + kk0;
    const __bf16* gA1 = repb + (size_t)(r0 + row1) * 1024 + kk1;
    const __bf16* gB0 = bagb + (size_t)(c0 + row0) * 1024 + kk0;
    const __bf16* gB1 = bagb + (size_t)(c0 + row1) * 1024 + kk1;

    for (int k0 = 0; k0 < 1024; k0 += 32) {
        __syncthreads();
        gll16(gA0 + k0, Al + i0);
        gll16(gA1 + k0, Al + i1);
        gll16(gB0 + k0, Bl + i0);
        gll16(gB1 + k0, Bl + i1);
        __syncthreads();
        bf16x8 a[4], bf[4];
        #pragma unroll
        for (int i = 0; i < 4; i++) a[i]  = *(const bf16x8*)(&Al[(wr0 + i * 16 + m) * 32 + quad * 8]);
        #pragma unroll
        for (int n = 0; n < 4; n++) bf[n] = *(const bf16x8*)(&Bl[(wc0 + n * 16 + m) * 32 + quad * 8]);
        #pragma unroll
        for (int i = 0; i < 4; i++)
            #pragma unroll
            for (int n = 0; n < 4; n++)
                acc[i][n] = __builtin_amdgcn_mfma_f32_16x16x32_bf16(a[i], bf[n], acc[i][n], 0, 0, 0);
    }

    const float invT = 1.0f / *temp;
    float nrv[16];
    #pragma unroll
    for (int i = 0; i < 4; i++)
        #pragma unroll
        for (int g = 0; g < 4; g++)
            nrv[i * 4 + g] = nr[r0 + wr0 + i * 16 + quad * 4 + g];
    #pragma unroll
    for (int n = 0; n < 4; n++) {
        const int c = c0 + wc0 + n * 16 + m;
        const float nbv = nb[c];
        #pragma unroll
        for (int i = 0; i < 4; i++) {
            #pragma unroll
            for (int g = 0; g < 4; g++) {
                const int r = r0 + wr0 + i * 16 + quad * 4 + g;
                float pair = acc[i][n][g] / fmaxf(nbv * nrv[i * 4 + g], 1e-8f);
                E[(size_t)r * 512 + c] = __expf(pair * invT);
            }
        }
    }
}

// ---- k5: neg + per-element loss; 256 blocks (j x ctile), 4 waves split b ----
__global__ __launch_bounds__(256) void k5_neg(
    const float* __restrict__ E, const float* __restrict__ pos_sim,
    const float* __restrict__ temp, float* __restrict__ bsums)
{
    const int ct = blockIdx.x & 7, j = blockIdx.x >> 3;
    const int t = threadIdx.x, lane = t & 63, w = t >> 6;
    const int c = ct * 64 + lane;
    __shared__ float red[4][64];

    float s = 0.f;
    const float* base = E + (size_t)j * 512 + c;
    #pragma unroll 8
    for (int b = w * 128; b < w * 128 + 128; b++)
        s += base[(size_t)b * 32 * 512];
    red[w][lane] = s;
    __syncthreads();

    if (t < 64) {
        const int cc = ct * 64 + t;
        float S = red[0][t] + red[1][t] + red[2][t] + red[3][t];
        S -= E[(size_t)((cc << 5) + j) * 512 + cc];    // exact diagonal cancellation
        const float invT = 1.0f / *temp;
        const float lp = pos_sim[(cc << 5) + j] * invT;
        float term = logf(__expf(lp) + S) - lp;
        term = wsum(term);
        if (t == 0) bsums[blockIdx.x] = term;
    }
}

__global__ __launch_bounds__(256) void k6_final(const float* __restrict__ bsums, float* __restrict__ loss)
{
    const int t = threadIdx.x;
    float v = bsums[t];
    v = wsum(v);
    __shared__ float r[4];
    if ((t & 63) == 0) r[t >> 6] = v;
    __syncthreads();
    if (t == 0) *loss = (r[0] + r[1] + r[2] + r[3]) * (1.0f / 16384.0f);
}

extern "C" void kernel_launch(void* const* d_in, const int* in_sizes, int n_in,
                              void* d_out, int out_size, void* d_ws, size_t ws_size,
                              hipStream_t stream)
{
    const float* sent = (const float*)d_in[0];
    const float* aug  = (const float*)d_in[1];
    const float* rel  = (const float*)d_in[2];
    const float* clsw = (const float*)d_in[3];
    const float* clsb = (const float*)d_in[4];
    const int*   lab  = (const int*)d_in[5];
    const float* temp = (const float*)d_in[6];
    float* out = (float*)d_out;

    char* ws = (char*)d_ws;
    float*  bag   = (float*)(ws);                          // 2 MB
    __bf16* bagb  = (__bf16*)(ws + (2u << 20));            // 1 MB
    float*  nb    = (float*)(ws + (3u << 20));             // 2 KB
    float*  nr    = (float*)(ws + (3u << 20) + 65536);     // 64 KB
    float*  pos   = (float*)(ws + (3u << 20) + 2 * 65536); // 64 KB
    __bf16* cwb   = (__bf16*)(ws + (3u << 20) + 3 * 65536);// 128 KB (64x1024 bf16)
    __bf16* repb  = (__bf16*)(ws + (4u << 20));            // 32 MB
    float*  E     = (float*)(ws + (36u << 20));            // 32 MB
    float*  bsums = (float*)(ws + (68u << 20));            // 1 KB

    k0_cvt  <<<256, 256, 0, stream>>>(clsw, cwb);
    k1_bag  <<<512, 1024, 0, stream>>>(sent, rel, lab, bag, bagb, nb);
    k2_norms<<<16384, 256, 0, stream>>>(sent, aug, repb, nr, pos);
    k3m     <<<8, 256, 0, stream>>>(bagb, cwb, clsb, out);
    k4_gemm <<<dim3(4, 128), 256, 0, stream>>>(repb, bagb, nr, nb, temp, E);
    k5_neg  <<<256, 256, 0, stream>>>(E, pos, temp, bsums);
    k6_final<<<1, 256, 0, stream>>>(bsums, out + 27136);
}